// Round 7
// baseline (365.553 us; speedup 1.0000x reference)
//
#include <hip/hip_runtime.h>

#define DH 30
#define SLOPE 0.01f

// Weights read via the scalar pipe (wave-uniform, compile-time offsets ->
// s_load -> SGPR -> v_fma with SGPR operand). Two samples per thread to
// amortize the weight s_load stream and double latency hiding.
__global__ __launch_bounds__(256) void mlp_fwdbwd(
    const float4* __restrict__ pe,
    const float*  __restrict__ q,
    const float4* __restrict__ s,
    const float* __restrict__ W1, const float* __restrict__ b1,
    const float* __restrict__ W2, const float* __restrict__ b2,
    const float* __restrict__ W3, const float* __restrict__ b3,
    const float* __restrict__ W4, const float* __restrict__ b4,
    float* __restrict__ dout, int n)
{
    const int t = blockIdx.x * 256 + threadIdx.x;
    const int half = (n + 1) >> 1;
    if (t >= half) return;
    const bool has2 = (t + half) < n;
    const int i0 = t;
    const int i1 = has2 ? (t + half) : t;   // safe address; stores guarded

    float x[2][9];
    {
        const float4 a = pe[i0]; const float4 b = s[i0]; const float qq = q[i0];
        x[0][0]=a.x; x[0][1]=a.y; x[0][2]=a.z; x[0][3]=a.w; x[0][4]=qq;
        x[0][5]=b.x; x[0][6]=b.y; x[0][7]=b.z; x[0][8]=b.w;
    }
    {
        const float4 a = pe[i1]; const float4 b = s[i1]; const float qq = q[i1];
        x[1][0]=a.x; x[1][1]=a.y; x[1][2]=a.z; x[1][3]=a.w; x[1][4]=qq;
        x[1][5]=b.x; x[1][6]=b.y; x[1][7]=b.z; x[1][8]=b.w;
    }

    float acc[2][DH];
    float h[2][DH];
    unsigned m1[2] = {0,0}, m2[2] = {0,0}, m3[2] = {0,0};

    // ---- layer 1: (x @ W1) then + b1 (acc from 0, k ascending, FMA) ----
    #pragma unroll
    for (int u = 0; u < 2; ++u)
        #pragma unroll
        for (int j = 0; j < DH; ++j) acc[u][j] = 0.f;
    #pragma unroll
    for (int k = 0; k < 9; ++k) {
        #pragma unroll
        for (int j = 0; j < DH; ++j) {
            const float w = W1[k * DH + j];
            acc[0][j] = fmaf(x[0][k], w, acc[0][j]);
            acc[1][j] = fmaf(x[1][k], w, acc[1][j]);
        }
    }
    #pragma unroll
    for (int j = 0; j < DH; ++j) {
        const float bb = b1[j];
        #pragma unroll
        for (int u = 0; u < 2; ++u) {
            const float z = acc[u][j] + bb;
            if (z > 0.f) m1[u] |= (1u << j);
            h[u][j] = (z > 0.f) ? z : SLOPE * z;
        }
    }

    // ---- layer 2 ----
    #pragma unroll
    for (int u = 0; u < 2; ++u)
        #pragma unroll
        for (int j = 0; j < DH; ++j) acc[u][j] = 0.f;
    #pragma unroll
    for (int k = 0; k < DH; ++k) {
        #pragma unroll
        for (int j = 0; j < DH; ++j) {
            const float w = W2[k * DH + j];
            acc[0][j] = fmaf(h[0][k], w, acc[0][j]);
            acc[1][j] = fmaf(h[1][k], w, acc[1][j]);
        }
    }
    #pragma unroll
    for (int j = 0; j < DH; ++j) {
        const float bb = b2[j];
        #pragma unroll
        for (int u = 0; u < 2; ++u) {
            const float z = acc[u][j] + bb;
            if (z > 0.f) m2[u] |= (1u << j);
            h[u][j] = (z > 0.f) ? z : SLOPE * z;
        }
    }

    // ---- layer 3 + output dot ----
    #pragma unroll
    for (int u = 0; u < 2; ++u)
        #pragma unroll
        for (int j = 0; j < DH; ++j) acc[u][j] = 0.f;
    #pragma unroll
    for (int k = 0; k < DH; ++k) {
        #pragma unroll
        for (int j = 0; j < DH; ++j) {
            const float w = W3[k * DH + j];
            acc[0][j] = fmaf(h[0][k], w, acc[0][j]);
            acc[1][j] = fmaf(h[1][k], w, acc[1][j]);
        }
    }
    float outv[2] = {0.f, 0.f};
    #pragma unroll
    for (int j = 0; j < DH; ++j) {
        const float bb = b3[j];
        const float w4 = W4[j];
        #pragma unroll
        for (int u = 0; u < 2; ++u) {
            const float z = acc[u][j] + bb;
            if (z > 0.f) m3[u] |= (1u << j);
            const float hz = (z > 0.f) ? z : SLOPE * z;
            outv[u] = fmaf(hz, w4, outv[u]);
        }
    }
    const float bb4 = b4[0];
    outv[0] += bb4; outv[1] += bb4;

    // ---- backward (mask-driven; value-continuous) ----
    float g[2][DH];
    #pragma unroll
    for (int j = 0; j < DH; ++j) {
        const float w = W4[j];
        const float ws = SLOPE * w;
        g[0][j] = ((m3[0] >> j) & 1u) ? w : ws;
        g[1][j] = ((m3[1] >> j) & 1u) ? w : ws;
    }
    float g2[2][DH];
    #pragma unroll
    for (int k = 0; k < DH; ++k) {
        float d00 = 0.f, d01 = 0.f, d10 = 0.f, d11 = 0.f;
        #pragma unroll
        for (int j = 0; j < DH; j += 2) {
            const float wa = W3[k * DH + j];
            d00 = fmaf(g[0][j], wa, d00);
            d10 = fmaf(g[1][j], wa, d10);
            if (j + 1 < DH) {
                const float wb = W3[k * DH + j + 1];
                d01 = fmaf(g[0][j+1], wb, d01);
                d11 = fmaf(g[1][j+1], wb, d11);
            }
        }
        const float dot0 = d00 + d01;
        const float dot1 = d10 + d11;
        g2[0][k] = ((m2[0] >> k) & 1u) ? dot0 : SLOPE * dot0;
        g2[1][k] = ((m2[1] >> k) & 1u) ? dot1 : SLOPE * dot1;
    }
    #pragma unroll
    for (int k = 0; k < DH; ++k) {
        float d00 = 0.f, d01 = 0.f, d10 = 0.f, d11 = 0.f;
        #pragma unroll
        for (int j = 0; j < DH; j += 2) {
            const float wa = W2[k * DH + j];
            d00 = fmaf(g2[0][j], wa, d00);
            d10 = fmaf(g2[1][j], wa, d10);
            if (j + 1 < DH) {
                const float wb = W2[k * DH + j + 1];
                d01 = fmaf(g2[0][j+1], wb, d01);
                d11 = fmaf(g2[1][j+1], wb, d11);
            }
        }
        const float dot0 = d00 + d01;
        const float dot1 = d10 + d11;
        g[0][k] = ((m1[0] >> k) & 1u) ? dot0 : SLOPE * dot0;
        g[1][k] = ((m1[1] >> k) & 1u) ? dot1 : SLOPE * dot1;
    }
    float gx[2][9];
    #pragma unroll
    for (int k = 0; k < 9; ++k) {
        float d00 = 0.f, d01 = 0.f, d10 = 0.f, d11 = 0.f;
        #pragma unroll
        for (int j = 0; j < DH; j += 2) {
            const float wa = W1[k * DH + j];
            d00 = fmaf(g[0][j], wa, d00);
            d10 = fmaf(g[1][j], wa, d10);
            if (j + 1 < DH) {
                const float wb = W1[k * DH + j + 1];
                d01 = fmaf(g[0][j+1], wb, d01);
                d11 = fmaf(g[1][j+1], wb, d11);
            }
        }
        gx[0][k] = d00 + d01;
        gx[1][k] = d10 + d11;
    }

    // ---- stores: [out(N) | h_s(4N) | h_q(N) | h_pe(4N)] ----
    float4* hs  = reinterpret_cast<float4*>(dout + (size_t)n);
    float4* hpe = reinterpret_cast<float4*>(dout + (size_t)6 * n);

    dout[i0] = outv[0];
    hs[i0]   = make_float4(gx[0][5], gx[0][6], gx[0][7], gx[0][8]);
    dout[(size_t)5 * n + i0] = gx[0][4];
    hpe[i0]  = make_float4(gx[0][0], gx[0][1], gx[0][2], gx[0][3]);
    if (has2) {
        dout[i1] = outv[1];
        hs[i1]   = make_float4(gx[1][5], gx[1][6], gx[1][7], gx[1][8]);
        dout[(size_t)5 * n + i1] = gx[1][4];
        hpe[i1]  = make_float4(gx[1][0], gx[1][1], gx[1][2], gx[1][3]);
    }
}

extern "C" void kernel_launch(void* const* d_in, const int* in_sizes, int n_in,
                              void* d_out, int out_size, void* d_ws, size_t ws_size,
                              hipStream_t stream) {
    const int n = in_sizes[1];  // input_q has N elements
    const int half = (n + 1) >> 1;
    const int blocks = (half + 255) / 256;
    hipLaunchKernelGGL(mlp_fwdbwd, dim3(blocks), dim3(256), 0, stream,
        (const float4*)d_in[0], (const float*)d_in[1], (const float4*)d_in[2],
        (const float*)d_in[3], (const float*)d_in[4],
        (const float*)d_in[5], (const float*)d_in[6],
        (const float*)d_in[7], (const float*)d_in[8],
        (const float*)d_in[9], (const float*)d_in[10],
        (float*)d_out, n);
}

// Round 8
// 214.122 us; speedup vs baseline: 1.7072x; 1.7072x over previous
//
#include <hip/hip_runtime.h>

#define DH 30
#define SLOPE 0.01f

typedef float v2 __attribute__((ext_vector_type(2)));

// Weights via scalar pipe (wave-uniform, compile-time offsets -> s_load ->
// SGPR pair -> v_pk_fma_f32 with SGPR-pair operand). 1 sample/thread (R7's
// 2-sample variant regressed: TLP loss > ILP gain). j-loops packed as
// float2: 30 independent accumulator chains -> per-component bit-identical.
__global__ __launch_bounds__(256) void mlp_fwdbwd(
    const float4* __restrict__ pe,
    const float*  __restrict__ q,
    const float4* __restrict__ s,
    const float* __restrict__ W1, const float* __restrict__ b1,
    const float* __restrict__ W2, const float* __restrict__ b2,
    const float* __restrict__ W3, const float* __restrict__ b3,
    const float* __restrict__ W4, const float* __restrict__ b4,
    float* __restrict__ dout, int n)
{
    const int i = blockIdx.x * 256 + threadIdx.x;
    if (i >= n) return;

    const float4 vpe = pe[i];
    const float4 vs  = s[i];
    const float  vq  = q[i];
    float x[9] = { vpe.x, vpe.y, vpe.z, vpe.w, vq, vs.x, vs.y, vs.z, vs.w };

    v2 acc[15];
    v2 hh[15];
    unsigned m1 = 0, m2 = 0, m3 = 0;

    // ---- layer 1: (x @ W1) then + b1 (acc from 0, k ascending, fma) ----
    #pragma unroll
    for (int jj = 0; jj < 15; ++jj) acc[jj] = (v2){0.f, 0.f};
    #pragma unroll
    for (int k = 0; k < 9; ++k) {
        const v2 xv = { x[k], x[k] };
        const v2* Wr = reinterpret_cast<const v2*>(W1 + k * DH);
        #pragma unroll
        for (int jj = 0; jj < 15; ++jj)
            acc[jj] = __builtin_elementwise_fma(xv, Wr[jj], acc[jj]);
    }
    {
        const v2* bv = reinterpret_cast<const v2*>(b1);
        #pragma unroll
        for (int jj = 0; jj < 15; ++jj) {
            const v2 z = acc[jj] + bv[jj];
            if (z.x > 0.f) m1 |= (1u << (2*jj));
            if (z.y > 0.f) m1 |= (1u << (2*jj+1));
            hh[jj].x = (z.x > 0.f) ? z.x : SLOPE * z.x;
            hh[jj].y = (z.y > 0.f) ? z.y : SLOPE * z.y;
        }
    }

    // ---- layer 2 ----
    #pragma unroll
    for (int jj = 0; jj < 15; ++jj) acc[jj] = (v2){0.f, 0.f};
    #pragma unroll
    for (int k = 0; k < DH; ++k) {
        const float hk = hh[k >> 1][k & 1];
        const v2 hv = { hk, hk };
        const v2* Wr = reinterpret_cast<const v2*>(W2 + k * DH);
        #pragma unroll
        for (int jj = 0; jj < 15; ++jj)
            acc[jj] = __builtin_elementwise_fma(hv, Wr[jj], acc[jj]);
    }
    {
        const v2* bv = reinterpret_cast<const v2*>(b2);
        #pragma unroll
        for (int jj = 0; jj < 15; ++jj) {
            const v2 z = acc[jj] + bv[jj];
            if (z.x > 0.f) m2 |= (1u << (2*jj));
            if (z.y > 0.f) m2 |= (1u << (2*jj+1));
            hh[jj].x = (z.x > 0.f) ? z.x : SLOPE * z.x;
            hh[jj].y = (z.y > 0.f) ? z.y : SLOPE * z.y;
        }
    }

    // ---- layer 3 ----
    #pragma unroll
    for (int jj = 0; jj < 15; ++jj) acc[jj] = (v2){0.f, 0.f};
    #pragma unroll
    for (int k = 0; k < DH; ++k) {
        const float hk = hh[k >> 1][k & 1];
        const v2 hv = { hk, hk };
        const v2* Wr = reinterpret_cast<const v2*>(W3 + k * DH);
        #pragma unroll
        for (int jj = 0; jj < 15; ++jj)
            acc[jj] = __builtin_elementwise_fma(hv, Wr[jj], acc[jj]);
    }
    // output dot: scalar, j ascending (bit-identical to passing R6 kernel)
    float outv = 0.f;
    #pragma unroll
    for (int j = 0; j < DH; ++j) {
        const float z = acc[j >> 1][j & 1] + b3[j];
        if (z > 0.f) m3 |= (1u << j);
        const float hz = (z > 0.f) ? z : SLOPE * z;
        outv = fmaf(hz, W4[j], outv);
    }
    outv += b4[0];

    // ---- backward (mask-driven; value-continuous, packed dots) ----
    v2 g3[15];
    {
        const v2* w4v = reinterpret_cast<const v2*>(W4);
        #pragma unroll
        for (int jj = 0; jj < 15; ++jj) {
            const v2 w = w4v[jj];
            g3[jj].x = ((m3 >> (2*jj))   & 1u) ? w.x : SLOPE * w.x;
            g3[jj].y = ((m3 >> (2*jj+1)) & 1u) ? w.y : SLOPE * w.y;
        }
    }
    v2 g2[15];
    #pragma unroll
    for (int k = 0; k < DH; ++k) {
        v2 d = (v2){0.f, 0.f};
        const v2* Wr = reinterpret_cast<const v2*>(W3 + k * DH);
        #pragma unroll
        for (int jj = 0; jj < 15; ++jj)
            d = __builtin_elementwise_fma(g3[jj], Wr[jj], d);
        const float dot = d.x + d.y;
        g2[k >> 1][k & 1] = ((m2 >> k) & 1u) ? dot : SLOPE * dot;
    }
    v2 g1[15];
    #pragma unroll
    for (int k = 0; k < DH; ++k) {
        v2 d = (v2){0.f, 0.f};
        const v2* Wr = reinterpret_cast<const v2*>(W2 + k * DH);
        #pragma unroll
        for (int jj = 0; jj < 15; ++jj)
            d = __builtin_elementwise_fma(g2[jj], Wr[jj], d);
        const float dot = d.x + d.y;
        g1[k >> 1][k & 1] = ((m1 >> k) & 1u) ? dot : SLOPE * dot;
    }
    float gx[9];
    #pragma unroll
    for (int k = 0; k < 9; ++k) {
        v2 d = (v2){0.f, 0.f};
        const v2* Wr = reinterpret_cast<const v2*>(W1 + k * DH);
        #pragma unroll
        for (int jj = 0; jj < 15; ++jj)
            d = __builtin_elementwise_fma(g1[jj], Wr[jj], d);
        gx[k] = d.x + d.y;
    }

    // ---- stores: [out(N) | h_s(4N) | h_q(N) | h_pe(4N)] ----
    dout[i] = outv;
    float4* hs = reinterpret_cast<float4*>(dout + (size_t)n);
    hs[i] = make_float4(gx[5], gx[6], gx[7], gx[8]);
    dout[(size_t)5 * n + i] = gx[4];
    float4* hpe = reinterpret_cast<float4*>(dout + (size_t)6 * n);
    hpe[i] = make_float4(gx[0], gx[1], gx[2], gx[3]);
}

extern "C" void kernel_launch(void* const* d_in, const int* in_sizes, int n_in,
                              void* d_out, int out_size, void* d_ws, size_t ws_size,
                              hipStream_t stream) {
    const int n = in_sizes[1];  // input_q has N elements
    const int blocks = (n + 255) / 256;
    hipLaunchKernelGGL(mlp_fwdbwd, dim3(blocks), dim3(256), 0, stream,
        (const float4*)d_in[0], (const float*)d_in[1], (const float4*)d_in[2],
        (const float*)d_in[3], (const float*)d_in[4],
        (const float*)d_in[5], (const float*)d_in[6],
        (const float*)d_in[7], (const float*)d_in[8],
        (const float*)d_in[9], (const float*)d_in[10],
        (float*)d_out, n);
}